// Round 10
// baseline (145.198 us; speedup 1.0000x reference)
//
#include <hip/hip_runtime.h>
#include <hip/hip_bf16.h>

#define BB 8
#define TT 2048
#define CC 1024
#define HH 64
#define NSPLIT 4

typedef __attribute__((ext_vector_type(8)))  short bf16x8;
typedef __attribute__((ext_vector_type(4)))  float f32x4;
typedef __attribute__((ext_vector_type(16))) float f32x16;
typedef __attribute__((ext_vector_type(8)))  unsigned short us8;
typedef unsigned int u32;

static __device__ __forceinline__ unsigned short f2bf(float f) {
    union { float f; unsigned int u; } v; v.f = f;
    unsigned int u = v.u;
    return (unsigned short)((u + 0x7FFFu + ((u >> 16) & 1u)) >> 16);  // RNE
}
static __device__ __forceinline__ float bf2f(unsigned short s) {
    union { u32 u; float f; } v; v.u = ((u32)s) << 16; return v.f;
}

// ---------------------------------------------------------------------------
// Kernel 0: W [C][H] fp32 -> Wt [3][H][C] bf16 (transposed), fold log2(e)/8
// into Wq so QK^T scores come out in the log2 domain. (unchanged)
// ---------------------------------------------------------------------------
__global__ __launch_bounds__(256) void prep_weights(
        const float* __restrict__ Wq, const float* __restrict__ Wk,
        const float* __restrict__ Wv, unsigned short* __restrict__ Wt) {
    __shared__ float tile[64][65];
    int w  = blockIdx.x >> 4;       // 0..2
    int c0 = (blockIdx.x & 15) * 64;
    const float* W = (w == 0) ? Wq : (w == 1) ? Wk : Wv;
    int li = threadIdx.x;
    {
        int c = li >> 2, h4 = (li & 3) * 16;
        const float* src = W + (size_t)(c0 + c) * HH + h4;
        #pragma unroll
        for (int i = 0; i < 4; ++i) {
            float4 v4 = *(const float4*)(src + i * 4);
            tile[c][h4 + i*4 + 0] = v4.x; tile[c][h4 + i*4 + 1] = v4.y;
            tile[c][h4 + i*4 + 2] = v4.z; tile[c][h4 + i*4 + 3] = v4.w;
        }
    }
    __syncthreads();
    float scale = (w == 0) ? 0.1803368802f : 1.0f;   // log2(e)/sqrt(64)
    int h = li >> 2, cg = (li & 3) * 16;
    unsigned short* dst = Wt + (size_t)w * HH * CC + (size_t)h * CC + c0 + cg;
    #pragma unroll
    for (int i = 0; i < 16; ++i) dst[i] = f2bf(tile[cg + i][h] * scale);
}

// ---------------------------------------------------------------------------
// Kernel 1: fused QKV projection, v6 — round-9 PASSED version, verbatim.
// ---------------------------------------------------------------------------
__global__ __launch_bounds__(512, 4) void proj_qkv(
        const float* __restrict__ x, const unsigned short* __restrict__ Wt,
        unsigned short* __restrict__ Pp) {
    __shared__ unsigned short Xs[2][64 * 64];    // 8 KB each
    __shared__ unsigned short Ws[2][192 * 64];   // 24 KB each
    int tid = threadIdx.x;
    int wv = tid >> 6, lane = tid & 63;
    int quad = (lane >> 4) & 3, lq = lane & 15;
    int mg = wv >> 2, ng = wv & 3;
    int r0 = blockIdx.x * 64;
    int k0 = blockIdx.y * 512;     // K-half base

    int xr = tid >> 3, xg = tid & 7;
    const float* xsrc = x + (size_t)(r0 + xr) * CC + k0 + xg * 8;
    int xdst = xr * 64 + ((xg ^ (xr & 7)) * 8);
    float4 xa[2], xb[2];                         // 2-deep prefetch sets

    f32x4 acc[2][3];
    #pragma unroll
    for (int mt = 0; mt < 2; ++mt)
        #pragma unroll
        for (int nt = 0; nt < 3; ++nt)
            #pragma unroll
            for (int i = 0; i < 4; ++i) acc[mt][nt][i] = 0.0f;

    auto stageW = [&](int buf, int kc) {
        #pragma unroll
        for (int i = 0; i < 3; ++i) {
            int fp = tid + i * 512;            // 0..1535
            int r = fp >> 3, pb = fp & 7, g = pb ^ (r & 7);
            const u32 __attribute__((address_space(1)))* gsrc =
                (const u32 __attribute__((address_space(1)))*)
                    (Wt + (size_t)r * CC + k0 + kc * 64 + g * 8);
            u32 __attribute__((address_space(3)))* ldst =
                (u32 __attribute__((address_space(3)))*)(&Ws[buf][fp * 8]);
            __builtin_amdgcn_global_load_lds(gsrc, ldst, 16, 0, 0);
        }
    };
    auto loadX = [&](int set, int kc) {
        xa[set] = *(const float4*)(xsrc + kc * 64);
        xb[set] = *(const float4*)(xsrc + kc * 64 + 4);
    };
    auto writeX = [&](int set, int buf) {
        unsigned short h[8];
        h[0]=f2bf(xa[set].x); h[1]=f2bf(xa[set].y);
        h[2]=f2bf(xa[set].z); h[3]=f2bf(xa[set].w);
        h[4]=f2bf(xb[set].x); h[5]=f2bf(xb[set].y);
        h[6]=f2bf(xb[set].z); h[7]=f2bf(xb[set].w);
        *(us8*)&Xs[buf][xdst] = *(const us8*)h;
    };

    loadX(0, 0); loadX(1, 1);
    stageW(0, 0);
    writeX(0, 0);

    for (int kc = 0; kc < 8; ++kc) {
        int cur = kc & 1;
        __syncthreads();                     // buf[cur] ready; buf[1-cur] free
        if (kc < 7) stageW(1 - cur, kc + 1);
        if (kc < 6) loadX(kc & 1, kc + 2);   // refill freed set
        #pragma unroll
        for (int ks = 0; ks < 2; ++ks) {
            int g = ks * 4 + quad;
            bf16x8 a[2], b[3];
            #pragma unroll
            for (int mt = 0; mt < 2; ++mt) {
                int arow = mg * 32 + mt * 16 + lq;
                a[mt] = *(const bf16x8*)&Xs[cur][arow * 64 + (g ^ (lq & 7)) * 8];
            }
            #pragma unroll
            for (int nt = 0; nt < 3; ++nt) {
                int brow = ng * 48 + nt * 16 + lq;
                b[nt] = *(const bf16x8*)&Ws[cur][brow * 64 + (g ^ (lq & 7)) * 8];
            }
            #pragma unroll
            for (int mt = 0; mt < 2; ++mt)
                #pragma unroll
                for (int nt = 0; nt < 3; ++nt)
                    acc[mt][nt] = __builtin_amdgcn_mfma_f32_16x16x32_bf16(
                        a[mt], b[nt], acc[mt][nt], 0, 0, 0);
        }
        if (kc < 7) writeX((kc + 1) & 1, 1 - cur);  // X[kc+1]
    }

    unsigned short* Pb =
        Pp + ((size_t)blockIdx.y * (BB * TT) + r0) * 192;
    #pragma unroll
    for (int mt = 0; mt < 2; ++mt) {
        #pragma unroll
        for (int nt = 0; nt < 3; ++nt) {
            int g = ng * 48 + nt * 16 + lq;
            #pragma unroll
            for (int i = 0; i < 4; ++i) {
                int row = mg * 32 + mt * 16 + quad * 4 + i;
                Pb[(size_t)row * 192 + g] = f2bf(acc[mt][nt][i]);
            }
        }
    }
}

// ---------------------------------------------------------------------------
// Kernel 1b: sum K-half partials -> qws (plain), kws (XOR-swizzled in 8-short
// blocks: phys = g ^ (row&7)), vws (chunk-major [b][jc][h][key], swizzled on
// h) so attn can stage K/V with straight global_load_lds copies.
// ---------------------------------------------------------------------------
__global__ __launch_bounds__(256) void qkv_reduce(
        const unsigned short* __restrict__ Pp,
        unsigned short* __restrict__ qws, unsigned short* __restrict__ kws,
        unsigned short* __restrict__ vws) {
    __shared__ unsigned short Vt[64][72];
    int t = threadIdx.x;
    int br0 = blockIdx.x * 64;
    const size_t H2 = (size_t)BB * TT * 192;   // K-half stride
    // phase 1: q,k (cols 0..127)
    {
        int r = br0 + (t >> 2), cg = (t & 3) * 32;
        const unsigned short* p0 = Pp + (size_t)r * 192 + cg;
        const unsigned short* p1 = p0 + H2;
        #pragma unroll
        for (int u = 0; u < 4; ++u) {
            us8 a = *(const us8*)(p0 + u * 8);
            us8 b = *(const us8*)(p1 + u * 8);
            unsigned short o[8];
            #pragma unroll
            for (int j = 0; j < 8; ++j) o[j] = f2bf(bf2f(a[j]) + bf2f(b[j]));
            if (cg < 64) {
                *(us8*)(qws + (size_t)r * HH + cg + u * 8) = *(const us8*)o;
            } else {
                int gb = ((cg - 64) >> 3) + u;          // logical 8-short block
                int pb = gb ^ (r & 7);                  // swizzled position
                *(us8*)(kws + (size_t)r * HH + pb * 8) = *(const us8*)o;
            }
        }
    }
    // phase 2: v (cols 128..191) -> transpose via LDS
    {
        int r = br0 + (t >> 2), ch = (t & 3) * 16;
        const unsigned short* p0 = Pp + (size_t)r * 192 + 128 + ch;
        const unsigned short* p1 = p0 + H2;
        #pragma unroll
        for (int u = 0; u < 2; ++u) {
            us8 a = *(const us8*)(p0 + u * 8);
            us8 b = *(const us8*)(p1 + u * 8);
            #pragma unroll
            for (int j = 0; j < 8; ++j)
                Vt[ch + u * 8 + j][r & 63] = f2bf(bf2f(a[j]) + bf2f(b[j]));
        }
    }
    __syncthreads();
    {   // phase 3: write chunk-major v: vws[((b*32+jc)*64 + h)*64 + key]
        int h = t >> 2, tb = (t & 3) * 16;
        int b = br0 >> 11, jc = (br0 & (TT - 1)) >> 6;
        unsigned short* base = vws + (((size_t)b * 32 + jc) * 64 + h) * 64;
        #pragma unroll
        for (int u = 0; u < 2; ++u) {
            int gb = (t & 3) * 2 + u;                  // logical key-block
            int pb = gb ^ (h & 7);                     // swizzled position
            *(us8*)(base + pb * 8) = *(const us8*)&Vt[h][tb + u * 8];
        }
    }
}

// ---------------------------------------------------------------------------
// Kernel 2: causal attention v5 (ROUND-10: the only changed kernel).
// proj-style pipeline ported to attn: BN=64 chunks (1/4 the barriers/key of
// v4), ONE barrier per chunk, K/V double-buffered via global_load_lds w=16
// (loads in flight across the whole compute phase; the barrier's vmcnt drain
// is the only sync), XOR-swizzled unpadded K/V LDS (conflict-free reads; v4's
// pitches 72/40 were 4-way conflicted), Ps pitch 66 (odd dwords, clean).
// Ps rows wave-private; O/L per-split bf16 partials unchanged. NSPLIT=4.
// ---------------------------------------------------------------------------
__global__ __launch_bounds__(128, 2) void attn(
        const unsigned short* __restrict__ qws,
        const unsigned short* __restrict__ kws,
        const unsigned short* __restrict__ vws,
        unsigned short* __restrict__ Op, float* __restrict__ Lp) {
    // K buf0 [0,4096) K buf1 [4096,8192) V buf0 [8192,12288) V buf1 [12288,16384)
    // Ps [16384, 16384+64*66)   (shorts)
    __shared__ unsigned short KV[16384 + 64 * 66];
    unsigned short* Ps = &KV[16384];
    int ti = blockIdx.x;            // 64-row q tile == 64-key chunk count-1
    int s  = blockIdx.y;            // kv split 0..3 (chunks jc = s, s+4, ...)
    int b  = blockIdx.z;
    if (s > ti) return;
    int tid = threadIdx.x, wv = tid >> 6, lane = tid & 63;
    int half = lane >> 5, l31 = lane & 31;

    bf16x8 qf[4];
    {
        const unsigned short* qp =
            qws + ((size_t)b * TT + ti * 64 + wv * 32 + l31) * HH + half * 8;
        #pragma unroll
        for (int ks = 0; ks < 4; ++ks) qf[ks] = *(const bf16x8*)(qp + ks * 16);
    }
    f32x16 O0, O1, Lc;
    #pragma unroll
    for (int i = 0; i < 16; ++i) { O0[i] = 0.f; O1[i] = 0.f; Lc[i] = 0.f; }
    bf16x8 ones;
    #pragma unroll
    for (int i = 0; i < 8; ++i) ones[i] = (short)0x3F80;

    auto stageKV = [&](int buf, int jc) {
        const unsigned short* kbase = kws + ((size_t)b * TT + jc * 64) * HH;
        const unsigned short* vbase = vws + (((size_t)b * 32 + jc) * 64) * 64;
        #pragma unroll
        for (int u = 0; u < 4; ++u) {
            int f = u * 128 + tid;             // 0..511, lane-contiguous/wave
            const u32 __attribute__((address_space(1)))* gk =
                (const u32 __attribute__((address_space(1)))*)(kbase + f * 8);
            u32 __attribute__((address_space(3)))* lk =
                (u32 __attribute__((address_space(3)))*)(&KV[buf * 4096 + f * 8]);
            __builtin_amdgcn_global_load_lds(gk, lk, 16, 0, 0);
            const u32 __attribute__((address_space(1)))* gv =
                (const u32 __attribute__((address_space(1)))*)(vbase + f * 8);
            u32 __attribute__((address_space(3)))* lv =
                (u32 __attribute__((address_space(3)))*)(&KV[8192 + buf * 4096 + f * 8]);
            __builtin_amdgcn_global_load_lds(gv, lv, 16, 0, 0);
        }
    };

    stageKV(0, s);
    int buf = 0;
    for (int jc = s; jc <= ti; jc += NSPLIT) {
        __syncthreads();                 // drains gll (vmcnt) + frees old buf
        if (jc + NSPLIT <= ti) stageKV(1 - buf, jc + NSPLIT);
        const unsigned short* Kc = &KV[buf * 4096];
        const unsigned short* Vc = &KV[8192 + buf * 4096];
        // S = Q K^T (log2-scaled)
        f32x16 S[2];
        #pragma unroll
        for (int i = 0; i < 16; ++i) { S[0][i] = 0.f; S[1][i] = 0.f; }
        #pragma unroll
        for (int nt = 0; nt < 2; ++nt)
            #pragma unroll
            for (int ks = 0; ks < 4; ++ks) {
                int row = nt * 32 + l31, gb = ks * 2 + half;
                bf16x8 kf = *(const bf16x8*)&Kc[row * 64 + (gb ^ (row & 7)) * 8];
                S[nt] = __builtin_amdgcn_mfma_f32_32x32x16_bf16(
                    qf[ks], kf, S[nt], 0, 0, 0);
            }
        bool diag = (jc == ti);
        #pragma unroll
        for (int nt = 0; nt < 2; ++nt)
            #pragma unroll
            for (int r = 0; r < 16; ++r) {
                int pat = (r & 3) + 8 * (r >> 2) + 4 * half;
                float p = __builtin_amdgcn_exp2f(S[nt][r]);
                if (diag && nt * 32 + l31 > wv * 32 + pat) p = 0.0f;
                Ps[(wv * 32 + pat) * 66 + nt * 32 + l31] = f2bf(p);
            }
        // O += P V ; L += P . ones   (Ps rows wave-private: no barrier)
        #pragma unroll
        for (int ks = 0; ks < 4; ++ks) {
            int gb = ks * 2 + half;
            bf16x8 pa = *(const bf16x8*)&Ps[(wv * 32 + l31) * 66 + ks * 16 + half * 8];
            bf16x8 vf0 = *(const bf16x8*)&Vc[l31 * 64 + (gb ^ (l31 & 7)) * 8];
            bf16x8 vf1 = *(const bf16x8*)&Vc[(32 + l31) * 64 + (gb ^ (l31 & 7)) * 8];
            O0 = __builtin_amdgcn_mfma_f32_32x32x16_bf16(pa, vf0, O0, 0, 0, 0);
            O1 = __builtin_amdgcn_mfma_f32_32x32x16_bf16(pa, vf1, O1, 0, 0, 0);
            Lc = __builtin_amdgcn_mfma_f32_32x32x16_bf16(pa, ones, Lc, 0, 0, 0);
        }
        buf = 1 - buf;
    }
    // deterministic per-split partial store (bf16)
    unsigned short* Ob =
        Op + (((size_t)s * BB + b) * TT + ti * 64 + wv * 32) * HH;
    #pragma unroll
    for (int r = 0; r < 16; ++r) {
        int pat = (r & 3) + 8 * (r >> 2) + 4 * half;
        Ob[(size_t)pat * HH + l31]      = f2bf(O0[r]);
        Ob[(size_t)pat * HH + 32 + l31] = f2bf(O1[r]);
    }
    if (l31 == 0) {
        #pragma unroll
        for (int r = 0; r < 16; ++r) {
            int pat = (r & 3) + 8 * (r >> 2) + 4 * half;
            Lp[((size_t)s * BB + b) * TT + ti * 64 + wv * 32 + pat] = Lc[r];
        }
    }
}

// ---------------------------------------------------------------------------
// Kernel 3: out = (sum_s Op[s]) / (sum_s Lp[s]). ns = min(ti+1, NSPLIT)
// splits exist per q-tile (64-key chunks now). 256 blocks x 256 threads.
// ---------------------------------------------------------------------------
__global__ __launch_bounds__(256) void norm_out(
        const unsigned short* __restrict__ Op, const float* __restrict__ Lp,
        float* __restrict__ out) {
    int idx = blockIdx.x * 256 + threadIdx.x;     // 65536 total
    int g = idx >> 2;                             // global row b*T + t, <16384
    int hseg = (idx & 3) * 16;
    int ti = (g & (TT - 1)) >> 6;
    int ns = min(ti + 1, NSPLIT);
    float a[16];
    #pragma unroll
    for (int j = 0; j < 16; ++j) a[j] = 0.f;
    float Ls = 0.f;
    for (int s = 0; s < ns; ++s) {
        const unsigned short* base =
            Op + ((size_t)s * BB * TT + g) * HH + hseg;
        us8 u0 = *(const us8*)base;
        us8 u1 = *(const us8*)(base + 8);
        #pragma unroll
        for (int j = 0; j < 8; ++j) { a[j] += bf2f(u0[j]); a[8 + j] += bf2f(u1[j]); }
        Ls += Lp[(size_t)s * BB * TT + g];
    }
    float inv = 1.0f / Ls;
    float* ob = out + (size_t)g * HH + hseg;
    #pragma unroll
    for (int q = 0; q < 4; ++q) {
        float4 v = make_float4(a[q*4] * inv, a[q*4+1] * inv,
                               a[q*4+2] * inv, a[q*4+3] * inv);
        ((float4*)ob)[q] = v;
    }
}

// ---------------------------------------------------------------------------
extern "C" void kernel_launch(void* const* d_in, const int* in_sizes, int n_in,
                              void* d_out, int out_size, void* d_ws, size_t ws_size,
                              hipStream_t stream) {
    (void)in_sizes; (void)n_in; (void)out_size; (void)ws_size;
    const float* x  = (const float*)d_in[0];
    const float* Wq = (const float*)d_in[1];
    const float* Wk = (const float*)d_in[2];
    const float* Wv = (const float*)d_in[3];
    float* out = (float*)d_out;

    char* ws = (char*)d_ws;
    unsigned short* Wt  = (unsigned short*)ws;                          // 384 KB
    unsigned short* qws = (unsigned short*)(ws + (1u << 19));           // 2 MB
    unsigned short* kws = (unsigned short*)(ws + (1u << 19) + (1u << 21));
    unsigned short* vws = (unsigned short*)(ws + (1u << 19) + (2u << 21)); // 2 MB
    unsigned short* Op  = (unsigned short*)(ws + (1u << 19) + (3u << 21)); // 8 MB bf16
    float*          Lp  = (float*)(ws + (1u << 19) + (3u << 21) + (1u << 24)); // 256 KB
    unsigned short* Pp  = (unsigned short*)(ws + (1u << 19) + (3u << 21)
                                            + (1u << 24) + (1u << 19));    // 12.6 MB

    prep_weights<<<48, 256, 0, stream>>>(Wq, Wk, Wv, Wt);
    proj_qkv<<<dim3(256, 2), 512, 0, stream>>>(x, Wt, Pp);
    qkv_reduce<<<256, 256, 0, stream>>>(Pp, qws, kws, vws);
    attn<<<dim3(32, NSPLIT, 8), 128, 0, stream>>>(qws, kws, vws, Op, Lp);
    norm_out<<<256, 256, 0, stream>>>(Op, Lp, out);
}